// Round 1
// baseline (172.616 us; speedup 1.0000x reference)
//
#include <hip/hip_runtime.h>
#include <hip/hip_bf16.h>

typedef __attribute__((ext_vector_type(8))) short sh8;        // 8 x bf16 bits (4 VGPR)
typedef __attribute__((ext_vector_type(16))) float fx16;      // MFMA 32x32 accumulator
typedef __attribute__((ext_vector_type(4))) unsigned int u32x4;

__device__ __forceinline__ unsigned short f2bits(float a) {
  union { __hip_bfloat16 h; unsigned short u; } c;
  c.h = __float2bfloat16(a);
  return c.u;
}
__device__ __forceinline__ unsigned int pk2(float a, float b) {
  return (unsigned int)f2bits(a) | ((unsigned int)f2bits(b) << 16);
}
__device__ __forceinline__ fx16 fzero16() {
  fx16 z;
  #pragma unroll
  for (int i = 0; i < 16; ++i) z[i] = 0.0f;
  return z;
}

// ---------------------------------------------------------------------------
// Kernel 1: batched Cayley transform Q = (I-A)(I+A)^-1 for P1 (64) and P2 (64).
// 16 lanes per matrix; Gauss-Jordan on [I+A | I-A]; right block ends as Q
// (valid since (I-A) and (I+A)^-1 commute). Well-conditioned, no pivoting.
// Qout layout: [mat][i][j] f32, mat 0..63 = cayley(P1), 64..127 = cayley(P2).
// ---------------------------------------------------------------------------
__global__ void k_cayley(const float* __restrict__ P1, const float* __restrict__ P2,
                         float* __restrict__ Qout) {
  int t = blockIdx.x * blockDim.x + threadIdx.x;
  int mat = t >> 4;
  int row = t & 15;
  if (mat >= 128) return;
  const float* P = (mat < 64) ? (P1 + mat * 256) : (P2 + (mat - 64) * 256);
  float M[16], Rr[16];
  #pragma unroll
  for (int j = 0; j < 16; ++j) {
    float a = 0.0f;
    if (j > row) a = P[row * 16 + j];       // A = triu(P,1) - triu(P,1)^T
    if (j < row) a = -P[j * 16 + row];
    float d = (j == row) ? 1.0f : 0.0f;
    M[j]  = d + a;                           // I + A
    Rr[j] = d - a;                           // I - A
  }
  int gbase = (threadIdx.x & 63) & ~15;      // 16-lane group base within wave
  #pragma unroll
  for (int k = 0; k < 16; ++k) {
    float pkk = __shfl(M[k], gbase + k);
    float inv = 1.0f / pkk;
    float pM[16], pR[16];
    #pragma unroll
    for (int j = 0; j < 16; ++j) {
      pM[j] = __shfl(M[j], gbase + k) * inv;
      pR[j] = __shfl(Rr[j], gbase + k) * inv;
    }
    if (row == k) {
      #pragma unroll
      for (int j = 0; j < 16; ++j) { M[j] = pM[j]; Rr[j] = pR[j]; }
    } else {
      float f = M[k];
      #pragma unroll
      for (int j = 0; j < 16; ++j) { M[j] -= f * pM[j]; Rr[j] -= f * pR[j]; }
    }
  }
  float* qo = Qout + mat * 256 + row * 16;
  #pragma unroll
  for (int j = 0; j < 16; ++j) qo[j] = Rr[j];
}

// ---------------------------------------------------------------------------
// Kernel 2: build folded weights in bf16, pre-arranged in MFMA B-fragment order.
//  B01[(j0j1,t2),(i0i1)] = sum_t1 C0[j0,t1,i0]*C1[j1,t2,t1,i1]   (1024 x 64)
//  B23[(t2,s),(j2j3)]    = sum_t3 C2[j2,t3,t2,i2]*C3[j3,t3,i3]   (1024 x 64)
// Storage: W[t2][tile(2)][kstep(4)][lane(64)][r(8)] bf16, where element is the
// B-operand frag value B[k = kstep*16 + (lane>>5)*8 + r, n = tile*32 + (lane&31)].
// W1: B = B01_t2^T (k=q, n=m) ; W2: B = B23_t2 (k=s, n).
// ---------------------------------------------------------------------------
__global__ void k_build(const float* __restrict__ P0, const float* __restrict__ P3,
                        const float* __restrict__ Qbuf,
                        unsigned short* __restrict__ W1, unsigned short* __restrict__ W2) {
  int t = blockIdx.x * blockDim.x + threadIdx.x;
  if (t >= 131072) return;
  const float* Q1 = Qbuf;
  const float* Q2 = Qbuf + 16384;
  int e  = t & 65535;
  int r  = e & 7;
  int l  = (e >> 3) & 63;
  int kx = (e >> 9) & 3;
  int mt = (e >> 11) & 1;
  int t2 = (e >> 12) & 15;
  int h8 = ((l >> 5) << 3);
  float acc = 0.0f;
  if (t < 65536) {
    int m = mt * 32 + (l & 31);
    int q = kx * 16 + h8 + r;
    int j0 = m >> 3, j1 = m & 7, i0 = q >> 3, i1 = q & 7;
    #pragma unroll
    for (int t1 = 0; t1 < 16; ++t1) {
      float c0 = P0[(j0 * 8 + (t1 >> 1)) * 16 + ((t1 & 1) * 8 + i0)];
      int a1 = j1 * 16 + t2, u1 = t1 * 8 + i1;
      float c1 = Q1[((a1 & 7) * 8 + (u1 >> 4)) * 256 + (a1 >> 3) * 16 + (u1 & 15)];
      acc += c0 * c1;
    }
    W1[e] = f2bits(acc);
  } else {
    int n = mt * 32 + (l & 31);
    int s = kx * 16 + h8 + r;
    int j2 = n >> 3, j3 = n & 7, i2 = s >> 3, i3 = s & 7;
    #pragma unroll
    for (int t3 = 0; t3 < 16; ++t3) {
      int a2 = j2 * 16 + t3, u2 = t2 * 8 + i2;
      float c2 = Q2[((a2 & 7) * 8 + (u2 >> 4)) * 256 + (a2 >> 3) * 16 + (u2 & 15)];
      float c3 = P3[((t3 & 7) * 8 + i3) * 16 + (j3 * 2 + (t3 >> 3))];
      acc += c2 * c3;
    }
    W2[e] = f2bits(acc);
  }
}

// ---------------------------------------------------------------------------
// Kernel 3: fused main. Per batch element b:
//   out_b(64x64) = reshape_{64x1024}(B01 @ X_b) @ B23 + bias
// computed as out_b = sum_{t2} (B01_t2 @ X_b) @ B23_t2, everything bf16 MFMA,
// Y passed GEMM1->GEMM2 in-register (pack + shfl lane^32 on verified C/D layout).
// WG = 256 thr (4 waves), 4 batch elems per WG (one per wave).
// ---------------------------------------------------------------------------
__global__ __launch_bounds__(256, 2) void k_main(
    const float* __restrict__ x,
    const unsigned short* __restrict__ W1,
    const unsigned short* __restrict__ W2,
    const float* __restrict__ bias,
    float* __restrict__ out) {
  __shared__ __align__(16) char smem[4 * 8192 + 16384];
  char* XsT = smem;              // [4 b][64 rows s][128 B] bf16 X_b^T, XOR-swizzled
  char* WLc = smem + 32768;      // [8 KB W1_t2][8 KB W2_t2] fragment-ordered

  const int tid  = threadIdx.x;
  const int lane = tid & 63;
  const int w    = tid >> 6;
  const int h    = lane >> 5;
  const int l31  = lane & 31;
  const size_t b0 = (size_t)blockIdx.x * 4;

  // ---- Stage X (f32 -> bf16, transposed to [s][q], swizzled) ----
  {
    const int s  = tid & 63;
    const int qw = (tid >> 6) * 16;
    const unsigned sw = ((unsigned)(s & 7)) << 4;
    for (int bb = 0; bb < 4; ++bb) {
      const float* xb = x + (b0 + bb) * 4096;
      unsigned int d[8];
      #pragma unroll
      for (int jj = 0; jj < 8; ++jj) {
        float a  = xb[(qw + 2 * jj + 0) * 64 + s];   // coalesced across lanes (s)
        float bq = xb[(qw + 2 * jj + 1) * 64 + s];
        d[jj] = pk2(a, bq);
      }
      char* base = XsT + bb * 8192 + s * 128;
      u32x4 v0 = {d[0], d[1], d[2], d[3]};
      u32x4 v1 = {d[4], d[5], d[6], d[7]};
      *(u32x4*)(base + (((unsigned)(qw * 2)) ^ sw))      = v0;
      *(u32x4*)(base + (((unsigned)(qw * 2 + 16)) ^ sw)) = v1;
    }
  }
  __syncthreads();

  fx16 accO[2][2];
  #pragma unroll
  for (int a = 0; a < 2; ++a)
    #pragma unroll
    for (int bq = 0; bq < 2; ++bq) accO[a][bq] = fzero16();

  const char* myX = XsT + w * 8192;

  for (int t2 = 0; t2 < 16; ++t2) {
    // ---- stage weights (16 KB) global -> LDS ----
    {
      const char* w1t = (const char*)(W1 + (size_t)t2 * 4096);
      const char* w2t = (const char*)(W2 + (size_t)t2 * 4096);
      int o = tid * 16;
      #pragma unroll
      for (int c = 0; c < 4; ++c) {
        int off = c * 4096 + o;
        const char* src = (c < 2) ? (w1t + off) : (w2t + (off - 8192));
        u32x4 v = *(const u32x4*)src;
        *(u32x4*)(WLc + off) = v;
      }
    }
    __syncthreads();

    // ---- GEMM1: Y^T(s,m) = X_b^T @ B01_t2^T ----
    sh8 af[2][4];
    #pragma unroll
    for (int st = 0; st < 2; ++st)
      #pragma unroll
      for (int kq = 0; kq < 4; ++kq) {
        int srow = st * 32 + l31;
        unsigned boff = (unsigned)srow * 128 +
                        (((unsigned)(kq * 32 + h * 16)) ^ (((unsigned)(srow & 7)) << 4));
        af[st][kq] = *(const sh8*)(myX + boff);
      }
    fx16 accY[2][2];
    #pragma unroll
    for (int a = 0; a < 2; ++a)
      #pragma unroll
      for (int bq = 0; bq < 2; ++bq) accY[a][bq] = fzero16();

    #pragma unroll
    for (int mt = 0; mt < 2; ++mt)
      #pragma unroll
      for (int kq = 0; kq < 4; ++kq) {
        sh8 bf = *(const sh8*)(WLc + ((mt * 4 + kq) * 64 + lane) * 16);
        accY[0][mt] = __builtin_amdgcn_mfma_f32_32x32x16_bf16(af[0][kq], bf, accY[0][mt], 0, 0, 0);
        accY[1][mt] = __builtin_amdgcn_mfma_f32_32x32x16_bf16(af[1][kq], bf, accY[1][mt], 0, 0, 0);
      }

    // ---- Y^T C/D (col=m=lane&31, row=s=(reg&3)+8*(reg>>2)+4*h) -> GEMM2 A-frags ----
    sh8 ga[2][4];
    #pragma unroll
    for (int st = 0; st < 2; ++st)
      #pragma unroll
      for (int mt = 0; mt < 2; ++mt) {
        fx16 Y = accY[st][mt];
        unsigned int P[8];
        P[0] = pk2(Y[0],  Y[1]);  P[1] = pk2(Y[2],  Y[3]);
        P[2] = pk2(Y[4],  Y[5]);  P[3] = pk2(Y[6],  Y[7]);
        P[4] = pk2(Y[8],  Y[9]);  P[5] = pk2(Y[10], Y[11]);
        P[6] = pk2(Y[12], Y[13]); P[7] = pk2(Y[14], Y[15]);
        unsigned int Qv[8];
        #pragma unroll
        for (int i = 0; i < 8; ++i) Qv[i] = (unsigned int)__shfl((int)P[i], lane ^ 32);
        u32x4 flo0 = {P[0], P[1], Qv[0], Qv[1]};
        u32x4 fhi0 = {Qv[2], Qv[3], P[2], P[3]};
        u32x4 flo1 = {P[4], P[5], Qv[4], Qv[5]};
        u32x4 fhi1 = {Qv[6], Qv[7], P[6], P[7]};
        u32x4 f0 = h ? fhi0 : flo0;
        u32x4 f1 = h ? fhi1 : flo1;
        union { u32x4 u; sh8 s8; } c0, c1;
        c0.u = f0; c1.u = f1;
        ga[mt][st * 2 + 0] = c0.s8;
        ga[mt][st * 2 + 1] = c1.s8;
      }

    // ---- GEMM2: out += Y @ B23_t2 ----
    #pragma unroll
    for (int nt = 0; nt < 2; ++nt)
      #pragma unroll
      for (int ks = 0; ks < 4; ++ks) {
        sh8 bf = *(const sh8*)(WLc + 8192 + ((nt * 4 + ks) * 64 + lane) * 16);
        accO[0][nt] = __builtin_amdgcn_mfma_f32_32x32x16_bf16(ga[0][ks], bf, accO[0][nt], 0, 0, 0);
        accO[1][nt] = __builtin_amdgcn_mfma_f32_32x32x16_bf16(ga[1][ks], bf, accO[1][nt], 0, 0, 0);
      }
    __syncthreads();
  }

  // ---- epilogue: out[b][m*64+n] = acc + bias ----
  float* ob = out + (b0 + (size_t)w) * 4096;
  #pragma unroll
  for (int mt = 0; mt < 2; ++mt)
    #pragma unroll
    for (int nt = 0; nt < 2; ++nt) {
      #pragma unroll
      for (int reg = 0; reg < 16; ++reg) {
        int m = mt * 32 + (reg & 3) + 8 * (reg >> 2) + 4 * h;
        int n = nt * 32 + l31;
        int o = m * 64 + n;
        ob[o] = accO[mt][nt][reg] + bias[o];
      }
    }
}

// ---------------------------------------------------------------------------
extern "C" void kernel_launch(void* const* d_in, const int* in_sizes, int n_in,
                              void* d_out, int out_size, void* d_ws, size_t ws_size,
                              hipStream_t stream) {
  (void)n_in; (void)out_size; (void)ws_size;
  const float* x    = (const float*)d_in[0];
  const float* P0   = (const float*)d_in[1];
  const float* P1   = (const float*)d_in[2];
  const float* P2   = (const float*)d_in[3];
  const float* P3   = (const float*)d_in[4];
  const float* bias = (const float*)d_in[5];
  float* out = (float*)d_out;

  // ws: Qbuf f32[128*256] (128 KB) | W1 bf16[65536] (128 KB) | W2 bf16[65536] (128 KB)
  float* Qbuf = (float*)d_ws;
  unsigned short* W1 = (unsigned short*)((char*)d_ws + 131072);
  unsigned short* W2 = (unsigned short*)((char*)d_ws + 262144);

  k_cayley<<<8, 256, 0, stream>>>(P1, P2, Qbuf);
  k_build<<<512, 256, 0, stream>>>(P0, P3, Qbuf, W1, W2);

  int batch = in_sizes[0] / 4096;
  k_main<<<batch / 4, 256, 0, stream>>>(x, W1, W2, bias, out);
}

// Round 2
// 168.056 us; speedup vs baseline: 1.0271x; 1.0271x over previous
//
#include <hip/hip_runtime.h>
#include <hip/hip_bf16.h>

typedef __attribute__((ext_vector_type(8))) short sh8;        // 8 x bf16 bits (4 VGPR)
typedef __attribute__((ext_vector_type(16))) float fx16;      // MFMA 32x32 accumulator
typedef __attribute__((ext_vector_type(4))) unsigned int u32x4;

__device__ __forceinline__ unsigned short f2bits(float a) {
  union { __hip_bfloat16 h; unsigned short u; } c;
  c.h = __float2bfloat16(a);
  return c.u;
}
__device__ __forceinline__ unsigned int pk2(float a, float b) {
  return (unsigned int)f2bits(a) | ((unsigned int)f2bits(b) << 16);
}
__device__ __forceinline__ fx16 fzero16() {
  fx16 z;
  #pragma unroll
  for (int i = 0; i < 16; ++i) z[i] = 0.0f;
  return z;
}

// v_permlane32_swap_b32 a, b:
//   for i in 0..31: tmp = a[i+32]; a[i+32] = b[i]; b[i] = tmp
// i.e. post: a = {a.lo, b.lo}, b = {a.hi_old, b.hi}
#define SWAP32(a, b) asm volatile("v_permlane32_swap_b32 %0, %1" : "+v"(a), "+v"(b))

// ---------------------------------------------------------------------------
// Kernel 1: batched Cayley transform Q = (I-A)(I+A)^-1 for P1 (64) and P2 (64).
// 16 lanes per matrix; Gauss-Jordan on [I+A | I-A]; right block ends as Q
// (valid since (I-A) and (I+A)^-1 commute). Well-conditioned, no pivoting.
// Qout layout: [mat][i][j] f32, mat 0..63 = cayley(P1), 64..127 = cayley(P2).
// ---------------------------------------------------------------------------
__global__ void k_cayley(const float* __restrict__ P1, const float* __restrict__ P2,
                         float* __restrict__ Qout) {
  int t = blockIdx.x * blockDim.x + threadIdx.x;
  int mat = t >> 4;
  int row = t & 15;
  if (mat >= 128) return;
  const float* P = (mat < 64) ? (P1 + mat * 256) : (P2 + (mat - 64) * 256);
  float M[16], Rr[16];
  #pragma unroll
  for (int j = 0; j < 16; ++j) {
    float a = 0.0f;
    if (j > row) a = P[row * 16 + j];       // A = triu(P,1) - triu(P,1)^T
    if (j < row) a = -P[j * 16 + row];
    float d = (j == row) ? 1.0f : 0.0f;
    M[j]  = d + a;                           // I + A
    Rr[j] = d - a;                           // I - A
  }
  int gbase = (threadIdx.x & 63) & ~15;      // 16-lane group base within wave
  #pragma unroll
  for (int k = 0; k < 16; ++k) {
    float pkk = __shfl(M[k], gbase + k);
    float inv = 1.0f / pkk;
    float pM[16], pR[16];
    #pragma unroll
    for (int j = 0; j < 16; ++j) {
      pM[j] = __shfl(M[j], gbase + k) * inv;
      pR[j] = __shfl(Rr[j], gbase + k) * inv;
    }
    if (row == k) {
      #pragma unroll
      for (int j = 0; j < 16; ++j) { M[j] = pM[j]; Rr[j] = pR[j]; }
    } else {
      float f = M[k];
      #pragma unroll
      for (int j = 0; j < 16; ++j) { M[j] -= f * pM[j]; Rr[j] -= f * pR[j]; }
    }
  }
  float* qo = Qout + mat * 256 + row * 16;
  #pragma unroll
  for (int j = 0; j < 16; ++j) qo[j] = Rr[j];
}

// ---------------------------------------------------------------------------
// Kernel 2: build folded weights in bf16, pre-arranged in MFMA B-fragment order.
//  B01[(j0j1,t2),(i0i1)] = sum_t1 C0[j0,t1,i0]*C1[j1,t2,t1,i1]   (1024 x 64)
//  B23[(t2,s),(j2j3)]    = sum_t3 C2[j2,t3,t2,i2]*C3[j3,t3,i3]   (1024 x 64)
// Storage: W[t2][tile(2)][kstep(4)][lane(64)][r(8)] bf16, where element is the
// B-operand frag value B[k = kstep*16 + (lane>>5)*8 + r, n = tile*32 + (lane&31)].
// W1: B = B01_t2^T (k=q, n=m) ; W2: B = B23_t2 (k=s, n).
// ---------------------------------------------------------------------------
__global__ void k_build(const float* __restrict__ P0, const float* __restrict__ P3,
                        const float* __restrict__ Qbuf,
                        unsigned short* __restrict__ W1, unsigned short* __restrict__ W2) {
  int t = blockIdx.x * blockDim.x + threadIdx.x;
  if (t >= 131072) return;
  const float* Q1 = Qbuf;
  const float* Q2 = Qbuf + 16384;
  int e  = t & 65535;
  int r  = e & 7;
  int l  = (e >> 3) & 63;
  int kx = (e >> 9) & 3;
  int mt = (e >> 11) & 1;
  int t2 = (e >> 12) & 15;
  int h8 = ((l >> 5) << 3);
  float acc = 0.0f;
  if (t < 65536) {
    int m = mt * 32 + (l & 31);
    int q = kx * 16 + h8 + r;
    int j0 = m >> 3, j1 = m & 7, i0 = q >> 3, i1 = q & 7;
    #pragma unroll
    for (int t1 = 0; t1 < 16; ++t1) {
      float c0 = P0[(j0 * 8 + (t1 >> 1)) * 16 + ((t1 & 1) * 8 + i0)];
      int a1 = j1 * 16 + t2, u1 = t1 * 8 + i1;
      float c1 = Q1[((a1 & 7) * 8 + (u1 >> 4)) * 256 + (a1 >> 3) * 16 + (u1 & 15)];
      acc += c0 * c1;
    }
    W1[e] = f2bits(acc);
  } else {
    int n = mt * 32 + (l & 31);
    int s = kx * 16 + h8 + r;
    int j2 = n >> 3, j3 = n & 7, i2 = s >> 3, i3 = s & 7;
    #pragma unroll
    for (int t3 = 0; t3 < 16; ++t3) {
      int a2 = j2 * 16 + t3, u2 = t2 * 8 + i2;
      float c2 = Q2[((a2 & 7) * 8 + (u2 >> 4)) * 256 + (a2 >> 3) * 16 + (u2 & 15)];
      float c3 = P3[((t3 & 7) * 8 + i3) * 16 + (j3 * 2 + (t3 >> 3))];
      acc += c2 * c3;
    }
    W2[e] = f2bits(acc);
  }
}

// ---------------------------------------------------------------------------
// Kernel 3: fused main, barrier-free. Per batch element b (one per wave):
//   out_b(64x64) = sum_{t2} (B01_t2 @ X_b) @ B23_t2 + bias
// X_b^T staged bf16+swizzled into wave-private LDS (no cross-wave deps),
// A-frags hoisted out of the t2 loop (loop-invariant), weight B-frags read
// straight from global (L2-resident, 256 KB total), Y passed GEMM1->GEMM2
// in-register via cvt-pack + v_permlane32_swap_b32.
// ---------------------------------------------------------------------------
__global__ __launch_bounds__(256, 2) void k_main(
    const float* __restrict__ x,
    const unsigned short* __restrict__ W1,
    const unsigned short* __restrict__ W2,
    const float* __restrict__ bias,
    float* __restrict__ out) {
  __shared__ __align__(16) char XsT[4 * 8192];   // [wave][64 rows s][128 B], swizzled

  const int tid  = threadIdx.x;
  const int lane = tid & 63;
  const int w    = tid >> 6;
  const int h    = lane >> 5;
  const int l31  = lane & 31;
  const size_t b = (size_t)blockIdx.x * 4 + w;

  char* myX = XsT + w * 8192;
  const float* xb = x + b * 4096;

  // ---- Stage own X_b (f32 -> bf16, transposed to [s][q], swizzled) ----
  {
    const int s = lane;
    const unsigned sw = ((unsigned)(s & 7)) << 4;
    char* base = myX + s * 128;
    #pragma unroll
    for (int c = 0; c < 4; ++c) {                 // 16 q-values per chunk
      unsigned int d[8];
      #pragma unroll
      for (int jj = 0; jj < 8; ++jj) {
        float a  = xb[(c * 16 + 2 * jj + 0) * 64 + s];  // 256B coalesced per instr
        float bq = xb[(c * 16 + 2 * jj + 1) * 64 + s];
        d[jj] = pk2(a, bq);
      }
      u32x4 v0 = {d[0], d[1], d[2], d[3]};
      u32x4 v1 = {d[4], d[5], d[6], d[7]};
      *(u32x4*)(base + (((unsigned)(c * 32)) ^ sw))      = v0;
      *(u32x4*)(base + (((unsigned)(c * 32 + 16)) ^ sw)) = v1;
    }
  }
  // wave-private write->read; force drain + pin ordering (no barrier needed)
  asm volatile("s_waitcnt lgkmcnt(0)" ::: "memory");
  __builtin_amdgcn_sched_barrier(0);

  // ---- Hoist GEMM1 A-frags (loop-invariant over t2): 8 x ds_read_b128 ----
  sh8 af[2][4];
  #pragma unroll
  for (int st = 0; st < 2; ++st)
    #pragma unroll
    for (int kq = 0; kq < 4; ++kq) {
      int srow = st * 32 + l31;
      unsigned boff = (unsigned)srow * 128 +
                      (((unsigned)(kq * 32 + h * 16)) ^ (((unsigned)(srow & 7)) << 4));
      af[st][kq] = *(const sh8*)(myX + boff);
    }

  fx16 accO[2][2];
  #pragma unroll
  for (int a = 0; a < 2; ++a)
    #pragma unroll
    for (int bq = 0; bq < 2; ++bq) accO[a][bq] = fzero16();

  const sh8* w1f = (const sh8*)W1;   // frag idx: t2*512 + (mt*4+kq)*64 + lane
  const sh8* w2f = (const sh8*)W2;

  #pragma unroll 2
  for (int t2 = 0; t2 < 16; ++t2) {
    // ---- GEMM1: Y^T(s,m) = X_b^T @ B01_t2^T ----
    sh8 b1[2][4];
    #pragma unroll
    for (int mt = 0; mt < 2; ++mt)
      #pragma unroll
      for (int kq = 0; kq < 4; ++kq)
        b1[mt][kq] = w1f[t2 * 512 + (mt * 4 + kq) * 64 + lane];

    fx16 accY[2][2];
    #pragma unroll
    for (int a = 0; a < 2; ++a)
      #pragma unroll
      for (int bq = 0; bq < 2; ++bq) accY[a][bq] = fzero16();

    __builtin_amdgcn_s_setprio(1);
    #pragma unroll
    for (int mt = 0; mt < 2; ++mt)
      #pragma unroll
      for (int kq = 0; kq < 4; ++kq) {
        accY[0][mt] = __builtin_amdgcn_mfma_f32_32x32x16_bf16(af[0][kq], b1[mt][kq], accY[0][mt], 0, 0, 0);
        accY[1][mt] = __builtin_amdgcn_mfma_f32_32x32x16_bf16(af[1][kq], b1[mt][kq], accY[1][mt], 0, 0, 0);
      }
    __builtin_amdgcn_s_setprio(0);

    // ---- Y^T C/D (col=m=lane&31, row=s=(reg&3)+8*(reg>>2)+4*h) -> GEMM2 A-frags
    // pack pairs then permlane32_swap: post-swap registers are directly the
    // fragment words for both wave halves (no selects).
    sh8 ga[2][4];
    #pragma unroll
    for (int st = 0; st < 2; ++st)
      #pragma unroll
      for (int mt = 0; mt < 2; ++mt) {
        fx16 Y = accY[st][mt];
        unsigned int P0 = pk2(Y[0],  Y[1]),  P1 = pk2(Y[2],  Y[3]);
        unsigned int P2 = pk2(Y[4],  Y[5]),  P3 = pk2(Y[6],  Y[7]);
        unsigned int P4 = pk2(Y[8],  Y[9]),  P5 = pk2(Y[10], Y[11]);
        unsigned int P6 = pk2(Y[12], Y[13]), P7 = pk2(Y[14], Y[15]);
        SWAP32(P0, P2); SWAP32(P1, P3);
        SWAP32(P4, P6); SWAP32(P5, P7);
        union { u32x4 u; sh8 s8; } c0, c1;
        c0.u = (u32x4){P0, P1, P2, P3};
        c1.u = (u32x4){P4, P5, P6, P7};
        ga[mt][st * 2 + 0] = c0.s8;
        ga[mt][st * 2 + 1] = c1.s8;
      }

    // ---- GEMM2: out += Y @ B23_t2 ----
    sh8 b2[2][4];
    #pragma unroll
    for (int nt = 0; nt < 2; ++nt)
      #pragma unroll
      for (int ks = 0; ks < 4; ++ks)
        b2[nt][ks] = w2f[t2 * 512 + (nt * 4 + ks) * 64 + lane];

    __builtin_amdgcn_s_setprio(1);
    #pragma unroll
    for (int nt = 0; nt < 2; ++nt)
      #pragma unroll
      for (int ks = 0; ks < 4; ++ks) {
        accO[0][nt] = __builtin_amdgcn_mfma_f32_32x32x16_bf16(ga[0][ks], b2[nt][ks], accO[0][nt], 0, 0, 0);
        accO[1][nt] = __builtin_amdgcn_mfma_f32_32x32x16_bf16(ga[1][ks], b2[nt][ks], accO[1][nt], 0, 0, 0);
      }
    __builtin_amdgcn_s_setprio(0);
  }

  // ---- epilogue: out[b][m*64+n] = acc + bias ----
  float* ob = out + b * 4096;
  #pragma unroll
  for (int mt = 0; mt < 2; ++mt)
    #pragma unroll
    for (int nt = 0; nt < 2; ++nt) {
      #pragma unroll
      for (int reg = 0; reg < 16; ++reg) {
        int m = mt * 32 + (reg & 3) + 8 * (reg >> 2) + 4 * h;
        int n = nt * 32 + l31;
        int o = m * 64 + n;
        ob[o] = accO[mt][nt][reg] + bias[o];
      }
    }
}

// ---------------------------------------------------------------------------
extern "C" void kernel_launch(void* const* d_in, const int* in_sizes, int n_in,
                              void* d_out, int out_size, void* d_ws, size_t ws_size,
                              hipStream_t stream) {
  (void)n_in; (void)out_size; (void)ws_size;
  const float* x    = (const float*)d_in[0];
  const float* P0   = (const float*)d_in[1];
  const float* P1   = (const float*)d_in[2];
  const float* P2   = (const float*)d_in[3];
  const float* P3   = (const float*)d_in[4];
  const float* bias = (const float*)d_in[5];
  float* out = (float*)d_out;

  // ws: Qbuf f32[128*256] (128 KB) | W1 bf16[65536] (128 KB) | W2 bf16[65536] (128 KB)
  float* Qbuf = (float*)d_ws;
  unsigned short* W1 = (unsigned short*)((char*)d_ws + 131072);
  unsigned short* W2 = (unsigned short*)((char*)d_ws + 262144);

  k_cayley<<<8, 256, 0, stream>>>(P1, P2, Qbuf);
  k_build<<<512, 256, 0, stream>>>(P0, P3, Qbuf, W1, W2);

  int batch = in_sizes[0] / 4096;
  k_main<<<batch / 4, 256, 0, stream>>>(x, W1, W2, bias, out);
}